// Round 4
// baseline (1785.346 us; speedup 1.0000x reference)
//
#include <hip/hip_runtime.h>
#include <hip/hip_bf16.h>

typedef __attribute__((ext_vector_type(8))) short bf16x8;
typedef __attribute__((ext_vector_type(4))) float f32x4;

#define EPSV 1e-5f
#define NN 50000
#define NE 800000
#define NG 64
#define MFMA16(a, b, c) __builtin_amdgcn_mfma_f32_16x16x32_bf16(a, b, c, 0, 0, 0)

__device__ __forceinline__ unsigned short f2bf(float f) {
  union { float f; unsigned u; } v; v.f = f;
  unsigned r = v.u + 0x7FFFu + ((v.u >> 16) & 1u);
  return (unsigned short)(r >> 16);
}

// ---------------- conversion kernels ----------------

__global__ __launch_bounds__(256) void cvt_vec_kernel(
    const float* __restrict__ x, const float* __restrict__ e,
    unsigned short* __restrict__ xb, unsigned short* __restrict__ eb) {
  const int NX4 = (NN * 128) / 4;
  const int NE4 = (NE * 32) / 4;
  const int total = NX4 + NE4;
  for (int idx = blockIdx.x * 256 + threadIdx.x; idx < total;
       idx += gridDim.x * 256) {
    float4 v = (idx < NX4) ? ((const float4*)x)[idx]
                           : ((const float4*)e)[idx - NX4];
    ushort4 o;
    o.x = f2bf(v.x); o.y = f2bf(v.y); o.z = f2bf(v.z); o.w = f2bf(v.w);
    if (idx < NX4) ((ushort4*)xb)[idx] = o;
    else           ((ushort4*)eb)[idx - NX4] = o;
  }
}

__global__ __launch_bounds__(256) void cvt_small_kernel(
    const float* __restrict__ u,
    const float* __restrict__ eW1, const float* __restrict__ eW2,
    const float* __restrict__ nW1, const float* __restrict__ nW2,
    unsigned short* __restrict__ ub,
    unsigned short* __restrict__ eW1T, unsigned short* __restrict__ eW2T,
    unsigned short* __restrict__ nW1T, unsigned short* __restrict__ nW2T) {
  int i = blockIdx.x * 256 + threadIdx.x;
  const int R0 = NG * 32;
  const int R1 = R0 + 128 * 320;
  const int R2 = R1 + 128 * 128;
  const int R3 = R2 + 128 * 320;
  const int R4 = R3 + 128 * 128;
  if (i < R0) {
    ub[i] = f2bf(u[i]);
  } else if (i < R1) {
    int j = i - R0; int n = j / 320, k = j % 320;
    eW1T[j] = f2bf(eW1[k * 128 + n]);
  } else if (i < R2) {
    int j = i - R1; int n = j / 128, k = j % 128;
    eW2T[j] = f2bf(eW2[k * 128 + n]);
  } else if (i < R3) {
    int j = i - R2; int n = j / 320, k = j % 320;
    nW1T[j] = (k < 288) ? f2bf(nW1[k * 128 + n]) : (unsigned short)0;
  } else if (i < R4) {
    int j = i - R3; int n = j / 128, k = j % 128;
    nW2T[j] = f2bf(nW2[k * 128 + n]);
  }
}

// ---------------- CSR construction ----------------

__global__ __launch_bounds__(256) void pre_kernel(
    const int* __restrict__ colIdx, int* __restrict__ cnt) {
  int i = blockIdx.x * 256 + threadIdx.x;
  if (i < NE) atomicAdd(&cnt[colIdx[i]], 1);
}

__global__ __launch_bounds__(1024) void scan_kernel(
    const int* __restrict__ cnt, int* __restrict__ offs,
    int* __restrict__ cur) {
  __shared__ int sums[1024];
  const int t = threadIdx.x;
  const int base = t * 49;
  int s = 0;
  for (int j = 0; j < 49; ++j) {
    int idx = base + j;
    if (idx < NN) s += cnt[idx];
  }
  sums[t] = s;
  __syncthreads();
  for (int off = 1; off < 1024; off <<= 1) {
    int add = (t >= off) ? sums[t - off] : 0;
    __syncthreads();
    sums[t] += add;
    __syncthreads();
  }
  int run = (t == 0) ? 0 : sums[t - 1];
  for (int j = 0; j < 49; ++j) {
    int idx = base + j;
    if (idx < NN) {
      offs[idx] = run; cur[idx] = run;
      run += cnt[idx];
    }
  }
}

__global__ __launch_bounds__(256) void fill_kernel(
    const int* __restrict__ colIdx, int* __restrict__ cur,
    int* __restrict__ eidlist) {
  int i = blockIdx.x * 256 + threadIdx.x;
  if (i < NE) {
    int p = atomicAdd(&cur[colIdx[i]], 1);
    eidlist[p] = i;
  }
}

// ---------------- edge MLP (persistent, fused e2g bins) ----------------
// 64 rows/tile, 256 thr = 4 waves; wave w owns rows w*16..+15 of each tile.
// No A/B LDS staging: MFMA fragments loaded directly from global (L2/L3-hot).
__global__ __launch_bounds__(256, 3) void edge_kernel(
    const unsigned short* __restrict__ eb, const unsigned short* __restrict__ xb,
    const unsigned short* __restrict__ ub,
    const int* __restrict__ rowI, const int* __restrict__ colI,
    const int* __restrict__ batch,
    const unsigned short* __restrict__ W1T,   // [128][320]
    const unsigned short* __restrict__ W2T,   // [128][128]
    const float* __restrict__ b1, const float* __restrict__ b2,
    const float* __restrict__ gam, const float* __restrict__ bet,
    float* __restrict__ outE, float* __restrict__ e2g_part) {
  __shared__ unsigned short Hsm[64][136];
  __shared__ float bins[NG * 128];
  __shared__ float cb1[128], cb2[128], cg[128], cbt[128];

  const int tid = threadIdx.x;
  if (tid < 128) {
    cb1[tid] = b1[tid]; cb2[tid] = b2[tid];
    cg[tid] = gam[tid]; cbt[tid] = bet[tid];
  }
  for (int i = tid; i < NG * 128; i += 256) bins[i] = 0.f;
  __syncthreads();

  const int w = tid >> 6, lane = tid & 63;
  const int l15 = lane & 15, lg = lane >> 4;
  const unsigned short* pw1 = W1T + l15 * 320 + lg * 8;
  const unsigned short* pw2 = W2T + l15 * 128 + lg * 8;
  const unsigned short* ph  = &Hsm[w * 16 + l15][lg * 8];

  for (int tile = blockIdx.x; tile < NE / 64; tile += gridDim.x) {
    const int arow = tile * 64 + w * 16 + l15;
    const int snd = rowI[arow], rcv = colI[arow];
    const int g = batch[snd];
    const unsigned short* pe = eb + (size_t)arow * 32 + lg * 8;
    const unsigned short* pr = xb + (size_t)rcv * 128 + lg * 8;
    const unsigned short* ps = xb + (size_t)snd * 128 + lg * 8;
    const unsigned short* pu = ub + g * 32 + lg * 8;

    f32x4 acc[8];
#pragma unroll
    for (int ni = 0; ni < 8; ++ni) acc[ni] = f32x4{0.f, 0.f, 0.f, 0.f};

    // GEMM1: K=320 = 5 pairs of K32; A-frags straight from global sources
    const unsigned short* pa0s[5] = { pe,      pr + 32, pr + 96, ps + 32, ps + 96 };
    const unsigned short* pa1s[5] = { pr,      pr + 64, ps,      ps + 64, pu      };
#pragma unroll
    for (int kc = 0; kc < 5; ++kc) {
      bf16x8 A0 = *(const bf16x8*)pa0s[kc];
      bf16x8 A1 = *(const bf16x8*)pa1s[kc];
#pragma unroll
      for (int ni = 0; ni < 8; ++ni) {
        bf16x8 B0 = *(const bf16x8*)(pw1 + ni * 5120 + kc * 64);
        bf16x8 B1 = *(const bf16x8*)(pw1 + ni * 5120 + kc * 64 + 32);
        acc[ni] = MFMA16(A0, B0, acc[ni]);
        acc[ni] = MFMA16(A1, B1, acc[ni]);
      }
    }

    // h1 = relu(C1+b1) -> Hsm (wave-private 16-row slice)
#pragma unroll
    for (int ni = 0; ni < 8; ++ni) {
      const int ncol = l15 + ni * 16;
      const float bias = cb1[ncol];
#pragma unroll
      for (int reg = 0; reg < 4; ++reg)
        Hsm[w * 16 + lg * 4 + reg][ncol] = f2bf(fmaxf(acc[ni][reg] + bias, 0.f));
    }
    __syncthreads();

    // GEMM2: K=128 = 2 pairs
    f32x4 acc2[8];
#pragma unroll
    for (int ni = 0; ni < 8; ++ni) acc2[ni] = f32x4{0.f, 0.f, 0.f, 0.f};
#pragma unroll
    for (int kc = 0; kc < 2; ++kc) {
      bf16x8 A0 = *(const bf16x8*)(ph + kc * 64);
      bf16x8 A1 = *(const bf16x8*)(ph + kc * 64 + 32);
#pragma unroll
      for (int ni = 0; ni < 8; ++ni) {
        bf16x8 B0 = *(const bf16x8*)(pw2 + ni * 2048 + kc * 64);
        bf16x8 B1 = *(const bf16x8*)(pw2 + ni * 2048 + kc * 64 + 32);
        acc2[ni] = MFMA16(A0, B0, acc2[ni]);
        acc2[ni] = MFMA16(A1, B1, acc2[ni]);
      }
    }

    // epilogue: bias + relu + LayerNorm + store + e2g LDS bins
    float hv[8][4];
    float sreg[4] = {0.f, 0.f, 0.f, 0.f}, ssreg[4] = {0.f, 0.f, 0.f, 0.f};
#pragma unroll
    for (int ni = 0; ni < 8; ++ni) {
      const int ncol = l15 + ni * 16;
      const float bias = cb2[ncol];
#pragma unroll
      for (int reg = 0; reg < 4; ++reg) {
        const float h = fmaxf(acc2[ni][reg] + bias, 0.f);
        hv[ni][reg] = h;
        sreg[reg] += h; ssreg[reg] += h * h;
      }
    }
#pragma unroll
    for (int reg = 0; reg < 4; ++reg) {
      float s = sreg[reg], ss = ssreg[reg];
#pragma unroll
      for (int off = 1; off < 16; off <<= 1) {
        s += __shfl_xor(s, off, 64);
        ss += __shfl_xor(ss, off, 64);
      }
      sreg[reg] = s; ssreg[reg] = ss;
    }
#pragma unroll
    for (int reg = 0; reg < 4; ++reg) {
      const int grow = tile * 64 + w * 16 + lg * 4 + reg;
      const float mu = sreg[reg] * (1.f / 128.f);
      const float var = ssreg[reg] * (1.f / 128.f) - mu * mu;
      const float rstd = rsqrtf(var + EPSV);
      const int gq = __shfl(g, lg * 4 + reg);
#pragma unroll
      for (int ni = 0; ni < 8; ++ni) {
        const int ncol = l15 + ni * 16;
        const float y = cg[ncol] * (hv[ni][reg] - mu) * rstd + cbt[ncol];
        outE[(size_t)grow * 128 + ncol] = y;
        atomicAdd(&bins[gq * 128 + ncol], y);
      }
    }
    __syncthreads();  // Hsm safe to overwrite next tile
  }

  // flush per-block e2g partial (non-atomic)
  float* dst = e2g_part + (size_t)blockIdx.x * (NG * 128);
  for (int i = tid; i < NG * 128; i += 256) dst[i] = bins[i];
}

__global__ __launch_bounds__(256) void e2g_reduce_kernel(
    const float* __restrict__ part, float* __restrict__ e2g) {
  const int i = blockIdx.x * 256 + threadIdx.x;  // 8192 total
  float s = 0.f;
  for (int p = 0; p < 768; ++p) s += part[(size_t)p * (NG * 128) + i];
  e2g[i] = s;
}

// ---------------- node MLP (CSR gather + fused n2g) ----------------
__global__ __launch_bounds__(256, 3) void node_kernel(
    const unsigned short* __restrict__ xb, const unsigned short* __restrict__ ub,
    const float* __restrict__ aggsrc,   // outE [NE][128] f32
    const int* __restrict__ batch,
    const int* __restrict__ offs, const int* __restrict__ cnt,
    const int* __restrict__ eidlist,
    const unsigned short* __restrict__ W1T,   // [128][320] (cols 288+ zero)
    const unsigned short* __restrict__ W2T,
    const float* __restrict__ b1, const float* __restrict__ b2,
    const float* __restrict__ gam, const float* __restrict__ bet,
    float* __restrict__ outX, float* __restrict__ n2g) {
  __shared__ unsigned short Agg[64][136];   // aggregated edges (bf16); aliased as Hsm
  __shared__ float bins[NG * 128];
  __shared__ float cb1[128], cb2[128], cg[128], cbt[128];

  const int tid = threadIdx.x;
  if (tid < 128) {
    cb1[tid] = b1[tid]; cb2[tid] = b2[tid];
    cg[tid] = gam[tid]; cbt[tid] = bet[tid];
  }
  for (int i = tid; i < NG * 128; i += 256) bins[i] = 0.f;

  // ---- CSR gather-sum of e2 into Agg (4 threads per row, 32 cols each) ----
  {
    const int r = tid >> 2, q = tid & 3;
    const int grow = blockIdx.x * 64 + r;
    int start = 0, deg = 0;
    if (grow < NN) { start = offs[grow]; deg = cnt[grow]; }
    float4 a[8];
#pragma unroll
    for (int k = 0; k < 8; ++k) a[k] = float4{0.f, 0.f, 0.f, 0.f};
    int j = 0;
    for (; j + 2 <= deg; j += 2) {
      const int e0 = eidlist[start + j], e1 = eidlist[start + j + 1];
      const float4* s0 = (const float4*)(aggsrc + (size_t)e0 * 128 + q * 32);
      const float4* s1 = (const float4*)(aggsrc + (size_t)e1 * 128 + q * 32);
#pragma unroll
      for (int k = 0; k < 8; ++k) {
        float4 v0 = s0[k], v1 = s1[k];
        a[k].x += v0.x + v1.x; a[k].y += v0.y + v1.y;
        a[k].z += v0.z + v1.z; a[k].w += v0.w + v1.w;
      }
    }
    if (j < deg) {
      const int e0 = eidlist[start + j];
      const float4* s0 = (const float4*)(aggsrc + (size_t)e0 * 128 + q * 32);
#pragma unroll
      for (int k = 0; k < 8; ++k) {
        float4 v0 = s0[k];
        a[k].x += v0.x; a[k].y += v0.y; a[k].z += v0.z; a[k].w += v0.w;
      }
    }
#pragma unroll
    for (int k = 0; k < 8; ++k) {
      ushort4 o;
      o.x = f2bf(a[k].x); o.y = f2bf(a[k].y);
      o.z = f2bf(a[k].z); o.w = f2bf(a[k].w);
      *(ushort4*)&Agg[r][q * 32 + k * 4] = o;
    }
  }
  __syncthreads();

  const int w = tid >> 6, lane = tid & 63;
  const int l15 = lane & 15, lg = lane >> 4;
  const int nodeL = blockIdx.x * 64 + w * 16 + l15;
  const int nodeC = nodeL < NN ? nodeL : NN - 1;
  const int g = batch[nodeC];
  const unsigned short* px = xb + (size_t)nodeC * 128 + lg * 8;
  const unsigned short* pu = ub + g * 32 + lg * 8;
  const unsigned short* pw1 = W1T + l15 * 320 + lg * 8;
  const unsigned short* pw2 = W2T + l15 * 128 + lg * 8;
  const unsigned short* pag = &Agg[w * 16 + l15][lg * 8];

  f32x4 acc[8];
#pragma unroll
  for (int ni = 0; ni < 8; ++ni) acc[ni] = f32x4{0.f, 0.f, 0.f, 0.f};

  // GEMM1: K=288 -> 4 pairs (x:0-127, agg:128-255) + single (u:256-287)
  {
    bf16x8 A0, A1;
#pragma unroll
    for (int kc = 0; kc < 2; ++kc) {   // x halves
      A0 = *(const bf16x8*)(px + kc * 64);
      A1 = *(const bf16x8*)(px + kc * 64 + 32);
#pragma unroll
      for (int ni = 0; ni < 8; ++ni) {
        bf16x8 B0 = *(const bf16x8*)(pw1 + ni * 5120 + kc * 64);
        bf16x8 B1 = *(const bf16x8*)(pw1 + ni * 5120 + kc * 64 + 32);
        acc[ni] = MFMA16(A0, B0, acc[ni]);
        acc[ni] = MFMA16(A1, B1, acc[ni]);
      }
    }
#pragma unroll
    for (int kc = 0; kc < 2; ++kc) {   // agg halves (LDS)
      A0 = *(const bf16x8*)(pag + kc * 64);
      A1 = *(const bf16x8*)(pag + kc * 64 + 32);
#pragma unroll
      for (int ni = 0; ni < 8; ++ni) {
        bf16x8 B0 = *(const bf16x8*)(pw1 + ni * 5120 + 128 + kc * 64);
        bf16x8 B1 = *(const bf16x8*)(pw1 + ni * 5120 + 128 + kc * 64 + 32);
        acc[ni] = MFMA16(A0, B0, acc[ni]);
        acc[ni] = MFMA16(A1, B1, acc[ni]);
      }
    }
    A0 = *(const bf16x8*)pu;           // u (k 256-287), single
#pragma unroll
    for (int ni = 0; ni < 8; ++ni) {
      bf16x8 B0 = *(const bf16x8*)(pw1 + ni * 5120 + 256);
      acc[ni] = MFMA16(A0, B0, acc[ni]);
    }
  }
  __syncthreads();  // Agg reads done before Hsm (alias) writes across... wave-local but cheap

  unsigned short (*Hsm)[136] = Agg;  // alias: Agg dead
#pragma unroll
  for (int ni = 0; ni < 8; ++ni) {
    const int ncol = l15 + ni * 16;
    const float bias = cb1[ncol];
#pragma unroll
    for (int reg = 0; reg < 4; ++reg)
      Hsm[w * 16 + lg * 4 + reg][ncol] = f2bf(fmaxf(acc[ni][reg] + bias, 0.f));
  }
  __syncthreads();

  f32x4 acc2[8];
#pragma unroll
  for (int ni = 0; ni < 8; ++ni) acc2[ni] = f32x4{0.f, 0.f, 0.f, 0.f};
  const unsigned short* ph = &Hsm[w * 16 + l15][lg * 8];
#pragma unroll
  for (int kc = 0; kc < 2; ++kc) {
    bf16x8 A0 = *(const bf16x8*)(ph + kc * 64);
    bf16x8 A1 = *(const bf16x8*)(ph + kc * 64 + 32);
#pragma unroll
    for (int ni = 0; ni < 8; ++ni) {
      bf16x8 B0 = *(const bf16x8*)(pw2 + ni * 2048 + kc * 64);
      bf16x8 B1 = *(const bf16x8*)(pw2 + ni * 2048 + kc * 64 + 32);
      acc2[ni] = MFMA16(A0, B0, acc2[ni]);
      acc2[ni] = MFMA16(A1, B1, acc2[ni]);
    }
  }

  float hv[8][4];
  float sreg[4] = {0.f, 0.f, 0.f, 0.f}, ssreg[4] = {0.f, 0.f, 0.f, 0.f};
#pragma unroll
  for (int ni = 0; ni < 8; ++ni) {
    const int ncol = l15 + ni * 16;
    const float bias = cb2[ncol];
#pragma unroll
    for (int reg = 0; reg < 4; ++reg) {
      const float h = fmaxf(acc2[ni][reg] + bias, 0.f);
      hv[ni][reg] = h;
      sreg[reg] += h; ssreg[reg] += h * h;
    }
  }
#pragma unroll
  for (int reg = 0; reg < 4; ++reg) {
    float s = sreg[reg], ss = ssreg[reg];
#pragma unroll
    for (int off = 1; off < 16; off <<= 1) {
      s += __shfl_xor(s, off, 64);
      ss += __shfl_xor(ss, off, 64);
    }
    sreg[reg] = s; ssreg[reg] = ss;
  }
#pragma unroll
  for (int reg = 0; reg < 4; ++reg) {
    const int grow = blockIdx.x * 64 + w * 16 + lg * 4 + reg;
    if (grow >= NN) continue;
    const float mu = sreg[reg] * (1.f / 128.f);
    const float var = ssreg[reg] * (1.f / 128.f) - mu * mu;
    const float rstd = rsqrtf(var + EPSV);
    const int gq = __shfl(g, lg * 4 + reg);
#pragma unroll
    for (int ni = 0; ni < 8; ++ni) {
      const int ncol = l15 + ni * 16;
      const float y = cg[ncol] * (hv[ni][reg] - mu) * rstd + cbt[ncol];
      outX[(size_t)grow * 128 + ncol] = y;
      atomicAdd(&bins[gq * 128 + ncol], y);
    }
  }
  __syncthreads();
  // flush n2g over the block's tiny [gmin, gmax] range (batch sorted)
  const int first = blockIdx.x * 64;
  const int last = min(first + 63, NN - 1);
  const int gmin = batch[first], gmax = batch[last];
  const int cntf = (gmax - gmin + 1) * 128;
  for (int i = tid; i < cntf; i += 256)
    atomicAdd(&n2g[gmin * 128 + i], bins[gmin * 128 + i]);
}

// ---------------- global MLP (tiny) ----------------
__global__ __launch_bounds__(128) void glob_kernel(
    const float* __restrict__ u, const float* __restrict__ n2g,
    const float* __restrict__ e2g,
    const float* __restrict__ gW1, const float* __restrict__ gb1,
    const float* __restrict__ gW2, const float* __restrict__ gb2,
    const float* __restrict__ gg, const float* __restrict__ gbt,
    float* __restrict__ outU) {
  __shared__ float in[288];
  __shared__ float h1[128];
  __shared__ float red[4];
  const int g = blockIdx.x, t = threadIdx.x;
  if (t < 32) in[t] = u[g * 32 + t];
  in[32 + t] = n2g[g * 128 + t];
  in[160 + t] = e2g[g * 128 + t];
  __syncthreads();
  float a = gb1[t];
  for (int k = 0; k < 288; ++k) a += in[k] * gW1[k * 128 + t];
  h1[t] = fmaxf(a, 0.f);
  __syncthreads();
  float h = gb2[t];
  for (int k = 0; k < 128; ++k) h += h1[k] * gW2[k * 128 + t];
  h = fmaxf(h, 0.f);
  float s = h, ss = h * h;
  for (int off = 1; off < 64; off <<= 1) {
    s += __shfl_xor(s, off, 64);
    ss += __shfl_xor(ss, off, 64);
  }
  if ((t & 63) == 0) { red[(t >> 6) * 2] = s; red[(t >> 6) * 2 + 1] = ss; }
  __syncthreads();
  const float S = red[0] + red[2], SS = red[1] + red[3];
  const float mu = S * (1.f / 128.f);
  const float var = SS * (1.f / 128.f) - mu * mu;
  const float rstd = rsqrtf(var + EPSV);
  outU[g * 128 + t] = gg[t] * (h - mu) * rstd + gbt[t];
}

// ---------------- launch ----------------
extern "C" void kernel_launch(void* const* d_in, const int* in_sizes, int n_in,
                              void* d_out, int out_size, void* d_ws,
                              size_t ws_size, hipStream_t stream) {
  const float* x   = (const float*)d_in[0];
  const float* e   = (const float*)d_in[1];
  const float* u   = (const float*)d_in[2];
  const int* eidx  = (const int*)d_in[3];
  const int* batch = (const int*)d_in[4];
  const float* eW1 = (const float*)d_in[5];
  const float* eb1 = (const float*)d_in[6];
  const float* eW2 = (const float*)d_in[7];
  const float* eb2 = (const float*)d_in[8];
  const float* eg  = (const float*)d_in[9];
  const float* ebt = (const float*)d_in[10];
  const float* nW1 = (const float*)d_in[11];
  const float* nb1 = (const float*)d_in[12];
  const float* nW2 = (const float*)d_in[13];
  const float* nb2 = (const float*)d_in[14];
  const float* ng  = (const float*)d_in[15];
  const float* nbt = (const float*)d_in[16];
  const float* gW1 = (const float*)d_in[17];
  const float* gb1 = (const float*)d_in[18];
  const float* gW2 = (const float*)d_in[19];
  const float* gb2 = (const float*)d_in[20];
  const float* gg  = (const float*)d_in[21];
  const float* gbt = (const float*)d_in[22];

  char* ws = (char*)d_ws;
  float* e2g           = (float*)(ws + 0);          //    32,768
  float* n2g           = (float*)(ws + 32768);      //    32,768
  int*   cnt           = (int*)  (ws + 65536);      //   200,000
  int*   offs          = (int*)  (ws + 265536);     //   200,000
  int*   cur           = (int*)  (ws + 465536);     //   200,000
  int*   eidlist       = (int*)  (ws + 665536);     // 3,200,000
  float* e2g_part      = (float*)(ws + 3865536);    // 25,165,824 (768*32KB)
  unsigned short* xb   = (unsigned short*)(ws + 29031360);  // 12,800,000
  unsigned short* eb   = (unsigned short*)(ws + 41831360);  // 51,200,000
  unsigned short* ub   = (unsigned short*)(ws + 93031360);  //     4,096
  unsigned short* eW1T = (unsigned short*)(ws + 93035456);  //    81,920
  unsigned short* eW2T = (unsigned short*)(ws + 93117376);  //    32,768
  unsigned short* nW1T = (unsigned short*)(ws + 93150144);  //    81,920
  unsigned short* nW2T = (unsigned short*)(ws + 93232064);  //    32,768
  // total ws use: ~93.3 MB

  // zero e2g + n2g + cnt (contiguous)
  hipMemsetAsync(ws, 0, 265536, stream);

  cvt_vec_kernel<<<2048, 256, 0, stream>>>(x, e, xb, eb);
  cvt_small_kernel<<<456, 256, 0, stream>>>(u, eW1, eW2, nW1, nW2, ub, eW1T,
                                            eW2T, nW1T, nW2T);

  float* outX = (float*)d_out;                 // [50000][128]
  float* outE = outX + (size_t)NN * 128;       // [800000][128]
  float* outU = outE + (size_t)NE * 128;       // [64][128]

  const int* rowI = eidx;        // senders
  const int* colI = eidx + NE;   // receivers

  pre_kernel<<<(NE + 255) / 256, 256, 0, stream>>>(colI, cnt);
  scan_kernel<<<1, 1024, 0, stream>>>(cnt, offs, cur);
  fill_kernel<<<(NE + 255) / 256, 256, 0, stream>>>(colI, cur, eidlist);

  edge_kernel<<<768, 256, 0, stream>>>(eb, xb, ub, rowI, colI, batch,
                                       eW1T, eW2T, eb1, eb2, eg, ebt,
                                       outE, e2g_part);
  e2g_reduce_kernel<<<32, 256, 0, stream>>>(e2g_part, e2g);
  node_kernel<<<(NN + 63) / 64, 256, 0, stream>>>(
      xb, ub, outE, batch, offs, cnt, eidlist, nW1T, nW2T,
      nb1, nb2, ng, nbt, outX, n2g);
  glob_kernel<<<NG, 128, 0, stream>>>(u, n2g, e2g, gW1, gb1, gW2, gb2, gg, gbt,
                                      outU);
}

// Round 5
// 1355.578 us; speedup vs baseline: 1.3170x; 1.3170x over previous
//
#include <hip/hip_runtime.h>
#include <hip/hip_bf16.h>

typedef __attribute__((ext_vector_type(8))) short bf16x8;
typedef __attribute__((ext_vector_type(4))) float f32x4;

#define EPSV 1e-5f
#define NN 50000
#define NE 800000
#define NG 64

__device__ __forceinline__ unsigned short f2bf(float f) {
  union { float f; unsigned u; } v; v.f = f;
  unsigned r = v.u + 0x7FFFu + ((v.u >> 16) & 1u);
  return (unsigned short)(r >> 16);
}

// ---------------- conversion kernels ----------------

__global__ __launch_bounds__(256) void cvt_vec_kernel(
    const float* __restrict__ x, const float* __restrict__ e,
    unsigned short* __restrict__ xb, unsigned short* __restrict__ eb) {
  const int NX4 = (NN * 128) / 4;
  const int NE4 = (NE * 32) / 4;
  const int total = NX4 + NE4;
  for (int idx = blockIdx.x * 256 + threadIdx.x; idx < total;
       idx += gridDim.x * 256) {
    float4 v = (idx < NX4) ? ((const float4*)x)[idx]
                           : ((const float4*)e)[idx - NX4];
    ushort4 o;
    o.x = f2bf(v.x); o.y = f2bf(v.y); o.z = f2bf(v.z); o.w = f2bf(v.w);
    if (idx < NX4) ((ushort4*)xb)[idx] = o;
    else           ((ushort4*)eb)[idx - NX4] = o;
  }
}

__global__ __launch_bounds__(256) void cvt_small_kernel(
    const float* __restrict__ u,
    const float* __restrict__ eW1, const float* __restrict__ eW2,
    const float* __restrict__ nW1, const float* __restrict__ nW2,
    unsigned short* __restrict__ ub,
    unsigned short* __restrict__ eW1T, unsigned short* __restrict__ eW2T,
    unsigned short* __restrict__ nW1T, unsigned short* __restrict__ nW2T) {
  int i = blockIdx.x * 256 + threadIdx.x;
  const int R0 = NG * 32;
  const int R1 = R0 + 128 * 320;
  const int R2 = R1 + 128 * 128;
  const int R3 = R2 + 128 * 320;
  const int R4 = R3 + 128 * 128;
  if (i < R0) {
    ub[i] = f2bf(u[i]);
  } else if (i < R1) {
    int j = i - R0; int n = j / 320, k = j % 320;
    eW1T[j] = f2bf(eW1[k * 128 + n]);
  } else if (i < R2) {
    int j = i - R1; int n = j / 128, k = j % 128;
    eW2T[j] = f2bf(eW2[k * 128 + n]);
  } else if (i < R3) {
    int j = i - R2; int n = j / 320, k = j % 320;
    nW1T[j] = (k < 288) ? f2bf(nW1[k * 128 + n]) : (unsigned short)0;
  } else if (i < R4) {
    int j = i - R3; int n = j / 128, k = j % 128;
    nW2T[j] = f2bf(nW2[k * 128 + n]);
  }
}

// ---------------- CSR construction + edge gid ----------------

__global__ __launch_bounds__(256) void pre_kernel(
    const int* __restrict__ rowIdx, const int* __restrict__ colIdx,
    const int* __restrict__ batch, int* __restrict__ eg_arr,
    int* __restrict__ cnt) {
  int i = blockIdx.x * 256 + threadIdx.x;
  if (i < NE) {
    eg_arr[i] = batch[rowIdx[i]];
    atomicAdd(&cnt[colIdx[i]], 1);
  }
}

__global__ __launch_bounds__(1024) void scan_kernel(
    const int* __restrict__ cnt, int* __restrict__ offs,
    int* __restrict__ cur) {
  __shared__ int sums[1024];
  const int t = threadIdx.x;
  const int base = t * 49;
  int s = 0;
  for (int j = 0; j < 49; ++j) {
    int idx = base + j;
    if (idx < NN) s += cnt[idx];
  }
  sums[t] = s;
  __syncthreads();
  for (int off = 1; off < 1024; off <<= 1) {
    int add = (t >= off) ? sums[t - off] : 0;
    __syncthreads();
    sums[t] += add;
    __syncthreads();
  }
  int run = (t == 0) ? 0 : sums[t - 1];
  for (int j = 0; j < 49; ++j) {
    int idx = base + j;
    if (idx < NN) {
      offs[idx] = run; cur[idx] = run;
      run += cnt[idx];
    }
  }
}

__global__ __launch_bounds__(256) void fill_kernel(
    const int* __restrict__ colIdx, int* __restrict__ cur,
    int* __restrict__ eidlist) {
  int i = blockIdx.x * 256 + threadIdx.x;
  if (i < NE) {
    int p = atomicAdd(&cur[colIdx[i]], 1);
    eidlist[p] = i;
  }
}

// ---------------- fused MLP kernel (edge MODE=0 / node MODE=1) ----------------
// 64 rows per block, 256 threads = 4 waves; wave w owns rows w*16..w*16+15.
template <int MODE>
__global__ __launch_bounds__(256, 2) void mlp_kernel(
    const unsigned short* __restrict__ ebuf,
    const unsigned short* __restrict__ xb,
    const unsigned short* __restrict__ ub,
    const float* __restrict__ aggsrc,
    const int* __restrict__ rowIdx, const int* __restrict__ colIdx,
    const int* __restrict__ batch,
    const int* __restrict__ offs, const int* __restrict__ cnt,
    const int* __restrict__ eidlist,
    const unsigned short* __restrict__ W1T,
    const unsigned short* __restrict__ W2T,
    const float* __restrict__ b1, const float* __restrict__ b2,
    const float* __restrict__ gam, const float* __restrict__ bet,
    float* __restrict__ out, float* __restrict__ aggout, int nRows) {
  constexpr int USZ = (MODE == 1) ? 50176 : 41984;
  __shared__ __align__(16) char U[USZ];
  __shared__ __align__(16) unsigned short Bsm[128][72];
  __shared__ float cb1[128], cb2[128], cg[128], cbt[128];
  unsigned short (*Asm)[328] = (unsigned short(*)[328])U;
  unsigned short (*Hsm)[136] = (unsigned short(*)[136])U;
  float* bins = (float*)(U + 17408);

  const int tid = threadIdx.x;
  if (tid < 128) {
    cb1[tid] = b1[tid]; cb2[tid] = b2[tid];
    cg[tid] = gam[tid]; cbt[tid] = bet[tid];
  }

  // ---- stage A tile: 4 threads per row ----
  {
    const int r = tid >> 2, q = tid & 3;
    const int grow = blockIdx.x * 64 + r;
    if (MODE == 0) {
      const int rcv = colIdx[grow];
      const int snd = rowIdx[grow];
      const int g = batch[snd];
      const uint4* esrc = (const uint4*)(ebuf + (size_t)grow * 32);
      const uint4* xr = (const uint4*)(xb + (size_t)rcv * 128);
      const uint4* xs = (const uint4*)(xb + (size_t)snd * 128);
      const uint4* us = (const uint4*)(ub + g * 32);
#pragma unroll
      for (int c = 0; c < 10; ++c) {
        const int cc = q * 10 + c;
        uint4 v;
        if (cc < 4)       v = esrc[cc];
        else if (cc < 20) v = xr[cc - 4];
        else if (cc < 36) v = xs[cc - 20];
        else              v = us[cc - 36];
        *(uint4*)&Asm[r][cc * 8] = v;
      }
    } else {
      const bool valid = grow < nRows;
      const uint4 zero = {0u, 0u, 0u, 0u};
      if (valid) {
        const uint4* xs = (const uint4*)(xb + (size_t)grow * 128 + q * 32);
#pragma unroll
        for (int k = 0; k < 4; ++k) *(uint4*)&Asm[r][q * 32 + k * 8] = xs[k];
      } else {
#pragma unroll
        for (int k = 0; k < 4; ++k) *(uint4*)&Asm[r][q * 32 + k * 8] = zero;
      }
      float4 a[8];
#pragma unroll
      for (int k = 0; k < 8; ++k) a[k] = float4{0.f, 0.f, 0.f, 0.f};
      if (valid) {
        const int start = offs[grow];
        const int deg = cnt[grow];
        int j = 0;
        for (; j + 2 <= deg; j += 2) {
          const int e0 = eidlist[start + j], e1 = eidlist[start + j + 1];
          const float4* s0 = (const float4*)(aggsrc + (size_t)e0 * 128 + q * 32);
          const float4* s1 = (const float4*)(aggsrc + (size_t)e1 * 128 + q * 32);
#pragma unroll
          for (int k = 0; k < 8; ++k) {
            float4 v0 = s0[k], v1 = s1[k];
            a[k].x += v0.x + v1.x; a[k].y += v0.y + v1.y;
            a[k].z += v0.z + v1.z; a[k].w += v0.w + v1.w;
          }
        }
        if (j < deg) {
          const int e0 = eidlist[start + j];
          const float4* s0 = (const float4*)(aggsrc + (size_t)e0 * 128 + q * 32);
#pragma unroll
          for (int k = 0; k < 8; ++k) {
            float4 v0 = s0[k];
            a[k].x += v0.x; a[k].y += v0.y; a[k].z += v0.z; a[k].w += v0.w;
          }
        }
      }
#pragma unroll
      for (int k = 0; k < 8; ++k) {
        ushort4 o;
        o.x = f2bf(a[k].x); o.y = f2bf(a[k].y);
        o.z = f2bf(a[k].z); o.w = f2bf(a[k].w);
        *(ushort4*)&Asm[r][128 + q * 32 + k * 4] = o;
      }
      const int g = valid ? batch[grow] : 0;
      uint4 uv = valid ? *(const uint4*)(ub + g * 32 + q * 8) : zero;
      *(uint4*)&Asm[r][256 + q * 8] = uv;
      *(uint4*)&Asm[r][288 + q * 8] = zero;
    }
  }

  const int w = tid >> 6;
  const int lane = tid & 63;
  const int l15 = lane & 15, lg = lane >> 4;

  f32x4 acc[8];
#pragma unroll
  for (int ni = 0; ni < 8; ++ni) acc[ni] = f32x4{0.f, 0.f, 0.f, 0.f};

  // ---- GEMM1: C1[64x128] = A[64x320] @ W1 ----
  for (int kc = 0; kc < 5; ++kc) {
    {
      const int n = tid >> 1, half = tid & 1;
      const uint4* src = (const uint4*)(W1T + (size_t)n * 320 + kc * 64 + half * 32);
#pragma unroll
      for (int k = 0; k < 4; ++k)
        *(uint4*)&Bsm[n][half * 32 + k * 8] = src[k];
    }
    __syncthreads();
    bf16x8 a0 = *(bf16x8*)&Asm[w * 16 + l15][kc * 64 + lg * 8];
    bf16x8 a1 = *(bf16x8*)&Asm[w * 16 + l15][kc * 64 + 32 + lg * 8];
#pragma unroll
    for (int ni = 0; ni < 8; ++ni) {
      bf16x8 bb0 = *(bf16x8*)&Bsm[ni * 16 + l15][lg * 8];
      bf16x8 bb1 = *(bf16x8*)&Bsm[ni * 16 + l15][32 + lg * 8];
      acc[ni] = __builtin_amdgcn_mfma_f32_16x16x32_bf16(a0, bb0, acc[ni], 0, 0, 0);
      acc[ni] = __builtin_amdgcn_mfma_f32_16x16x32_bf16(a1, bb1, acc[ni], 0, 0, 0);
    }
    __syncthreads();
  }

  // ---- h1 = relu(C1 + b1) -> Hsm (aliases dead Asm); MODE1: zero bins ----
#pragma unroll
  for (int ni = 0; ni < 8; ++ni) {
    const int ncol = l15 + ni * 16;
    const float bias = cb1[ncol];
#pragma unroll
    for (int reg = 0; reg < 4; ++reg) {
      const int mrow = w * 16 + lg * 4 + reg;
      Hsm[mrow][ncol] = f2bf(fmaxf(acc[ni][reg] + bias, 0.f));
    }
  }
  if (MODE == 1) {
    for (int i = tid; i < NG * 128; i += 256) bins[i] = 0.f;
  }

  // ---- GEMM2: C2 = H1[64x128] @ W2 ----
  f32x4 acc2[8];
#pragma unroll
  for (int ni = 0; ni < 8; ++ni) acc2[ni] = f32x4{0.f, 0.f, 0.f, 0.f};
  for (int kc = 0; kc < 2; ++kc) {
    {
      const int n = tid >> 1, half = tid & 1;
      const uint4* src = (const uint4*)(W2T + (size_t)n * 128 + kc * 64 + half * 32);
#pragma unroll
      for (int k = 0; k < 4; ++k)
        *(uint4*)&Bsm[n][half * 32 + k * 8] = src[k];
    }
    __syncthreads();
    bf16x8 a0 = *(bf16x8*)&Hsm[w * 16 + l15][kc * 64 + lg * 8];
    bf16x8 a1 = *(bf16x8*)&Hsm[w * 16 + l15][kc * 64 + 32 + lg * 8];
#pragma unroll
    for (int ni = 0; ni < 8; ++ni) {
      bf16x8 bb0 = *(bf16x8*)&Bsm[ni * 16 + l15][lg * 8];
      bf16x8 bb1 = *(bf16x8*)&Bsm[ni * 16 + l15][32 + lg * 8];
      acc2[ni] = __builtin_amdgcn_mfma_f32_16x16x32_bf16(a0, bb0, acc2[ni], 0, 0, 0);
      acc2[ni] = __builtin_amdgcn_mfma_f32_16x16x32_bf16(a1, bb1, acc2[ni], 0, 0, 0);
    }
    __syncthreads();
  }

  // ---- epilogue ----
  float hv[8][4];
  float sreg[4] = {0.f, 0.f, 0.f, 0.f}, ssreg[4] = {0.f, 0.f, 0.f, 0.f};
#pragma unroll
  for (int ni = 0; ni < 8; ++ni) {
    const int ncol = l15 + ni * 16;
    const float bias = cb2[ncol];
#pragma unroll
    for (int reg = 0; reg < 4; ++reg) {
      const float h = fmaxf(acc2[ni][reg] + bias, 0.f);
      hv[ni][reg] = h;
      sreg[reg] += h; ssreg[reg] += h * h;
    }
  }
#pragma unroll
  for (int reg = 0; reg < 4; ++reg) {
    float s = sreg[reg], ss = ssreg[reg];
#pragma unroll
    for (int off = 1; off < 16; off <<= 1) {
      s += __shfl_xor(s, off, 64);
      ss += __shfl_xor(ss, off, 64);
    }
    sreg[reg] = s; ssreg[reg] = ss;
  }
#pragma unroll
  for (int reg = 0; reg < 4; ++reg) {
    const int mrow = w * 16 + lg * 4 + reg;
    const int grow = blockIdx.x * 64 + mrow;
    if (MODE == 1 && grow >= nRows) continue;
    const float mu = sreg[reg] * (1.f / 128.f);
    const float var = ssreg[reg] * (1.f / 128.f) - mu * mu;
    const float rstd = rsqrtf(var + EPSV);
    int g = 0;
    if (MODE == 1) g = batch[grow];
#pragma unroll
    for (int ni = 0; ni < 8; ++ni) {
      const int ncol = l15 + ni * 16;
      const float y = cg[ncol] * (hv[ni][reg] - mu) * rstd + cbt[ncol];
      out[(size_t)grow * 128 + ncol] = y;
      if (MODE == 1) atomicAdd(&bins[g * 128 + ncol], y);
    }
  }
  if (MODE == 1) {
    __syncthreads();
    const int first = blockIdx.x * 64;
    const int last = min(first + 63, nRows - 1);
    const int gmin = batch[first], gmax = batch[last];
    const int cntf = (gmax - gmin + 1) * 128;
    for (int i = tid; i < cntf; i += 256)
      atomicAdd(&aggout[gmin * 128 + i], bins[gmin * 128 + i]);
  }
}

// ---------------- edge->global segment sum (ILP-8, 1000 blocks) ----------------
__global__ __launch_bounds__(256) void seg_e2g_kernel(
    const float* __restrict__ data, const int* __restrict__ gid,
    float* __restrict__ part) {
  __shared__ float bins[NG * 128];
  const int t = threadIdx.x;
  for (int i = t; i < NG * 128; i += 256) bins[i] = 0.f;
  __syncthreads();
  const int start = blockIdx.x * 800;   // 1000 blocks x 800 rows
  const int col = t & 127, sub = t >> 7;
  for (int base = start + sub; base < start + 800; base += 16) {
    float v[8]; int g[8];
#pragma unroll
    for (int j = 0; j < 8; ++j) {
      const int pos = base + j * 2;
      v[j] = data[(size_t)pos * 128 + col];
      g[j] = gid[pos];
    }
#pragma unroll
    for (int j = 0; j < 8; ++j)
      atomicAdd(&bins[g[j] * 128 + col], v[j]);
  }
  __syncthreads();
  float* dst = part + (size_t)blockIdx.x * (NG * 128);
  for (int i = t; i < NG * 128; i += 256) dst[i] = bins[i];
}

__global__ __launch_bounds__(256) void e2g_reduce_kernel(
    const float* __restrict__ part, float* __restrict__ e2g) {
  const int i = blockIdx.x * 256 + threadIdx.x;  // 8192 total
  float s = 0.f;
  for (int p = 0; p < 1000; ++p) s += part[(size_t)p * (NG * 128) + i];
  e2g[i] = s;
}

// ---------------- global MLP (tiny) ----------------
__global__ __launch_bounds__(128) void glob_kernel(
    const float* __restrict__ u, const float* __restrict__ n2g,
    const float* __restrict__ e2g,
    const float* __restrict__ gW1, const float* __restrict__ gb1,
    const float* __restrict__ gW2, const float* __restrict__ gb2,
    const float* __restrict__ gg, const float* __restrict__ gbt,
    float* __restrict__ outU) {
  __shared__ float in[288];
  __shared__ float h1[128];
  __shared__ float red[4];
  const int g = blockIdx.x, t = threadIdx.x;
  if (t < 32) in[t] = u[g * 32 + t];
  in[32 + t] = n2g[g * 128 + t];
  in[160 + t] = e2g[g * 128 + t];
  __syncthreads();
  float a = gb1[t];
  for (int k = 0; k < 288; ++k) a += in[k] * gW1[k * 128 + t];
  h1[t] = fmaxf(a, 0.f);
  __syncthreads();
  float h = gb2[t];
  for (int k = 0; k < 128; ++k) h += h1[k] * gW2[k * 128 + t];
  h = fmaxf(h, 0.f);
  float s = h, ss = h * h;
  for (int off = 1; off < 64; off <<= 1) {
    s += __shfl_xor(s, off, 64);
    ss += __shfl_xor(ss, off, 64);
  }
  if ((t & 63) == 0) { red[(t >> 6) * 2] = s; red[(t >> 6) * 2 + 1] = ss; }
  __syncthreads();
  const float S = red[0] + red[2], SS = red[1] + red[3];
  const float mu = S * (1.f / 128.f);
  const float var = SS * (1.f / 128.f) - mu * mu;
  const float rstd = rsqrtf(var + EPSV);
  outU[g * 128 + t] = gg[t] * (h - mu) * rstd + gbt[t];
}

// ---------------- launch ----------------
extern "C" void kernel_launch(void* const* d_in, const int* in_sizes, int n_in,
                              void* d_out, int out_size, void* d_ws,
                              size_t ws_size, hipStream_t stream) {
  const float* x   = (const float*)d_in[0];
  const float* e   = (const float*)d_in[1];
  const float* u   = (const float*)d_in[2];
  const int* eidx  = (const int*)d_in[3];
  const int* batch = (const int*)d_in[4];
  const float* eW1 = (const float*)d_in[5];
  const float* eb1 = (const float*)d_in[6];
  const float* eW2 = (const float*)d_in[7];
  const float* eb2 = (const float*)d_in[8];
  const float* eg  = (const float*)d_in[9];
  const float* ebt = (const float*)d_in[10];
  const float* nW1 = (const float*)d_in[11];
  const float* nb1 = (const float*)d_in[12];
  const float* nW2 = (const float*)d_in[13];
  const float* nb2 = (const float*)d_in[14];
  const float* ng  = (const float*)d_in[15];
  const float* nbt = (const float*)d_in[16];
  const float* gW1 = (const float*)d_in[17];
  const float* gb1 = (const float*)d_in[18];
  const float* gW2 = (const float*)d_in[19];
  const float* gb2 = (const float*)d_in[20];
  const float* gg  = (const float*)d_in[21];
  const float* gbt = (const float*)d_in[22];

  char* ws = (char*)d_ws;
  float* e2g           = (float*)(ws + 0);          //    32,768
  float* n2g           = (float*)(ws + 32768);      //    32,768
  int*   cnt           = (int*)  (ws + 65536);      //   200,000
  int*   offs          = (int*)  (ws + 265536);     //   200,000
  int*   cur           = (int*)  (ws + 465536);     //   200,000
  int*   eidlist       = (int*)  (ws + 665536);     // 3,200,000
  int*   eg_arr        = (int*)  (ws + 3865536);    // 3,200,000
  unsigned short* xb   = (unsigned short*)(ws + 7065536);   // 12,800,000
  unsigned short* eb   = (unsigned short*)(ws + 19865536);  // 51,200,000
  unsigned short* ub   = (unsigned short*)(ws + 71065536);  //     4,096
  unsigned short* eW1T = (unsigned short*)(ws + 71069632);  //    81,920
  unsigned short* eW2T = (unsigned short*)(ws + 71151552);  //    32,768
  unsigned short* nW1T = (unsigned short*)(ws + 71184320);  //    81,920
  unsigned short* nW2T = (unsigned short*)(ws + 71266240);  //    32,768
  // e2g_part aliases eb (dead after mlp<0>); 1000 * 32 KB = 32.77 MB <= 51.2 MB
  float* e2g_part      = (float*)eb;
  // total ws use: ~71.3 MB

  // zero e2g + n2g + cnt (contiguous)
  hipMemsetAsync(ws, 0, 265536, stream);

  cvt_vec_kernel<<<2048, 256, 0, stream>>>(x, e, xb, eb);
  cvt_small_kernel<<<456, 256, 0, stream>>>(u, eW1, eW2, nW1, nW2, ub, eW1T,
                                            eW2T, nW1T, nW2T);

  float* outX = (float*)d_out;                 // [50000][128]
  float* outE = outX + (size_t)NN * 128;       // [800000][128]
  float* outU = outE + (size_t)NE * 128;       // [64][128]

  const int* rowI = eidx;        // senders
  const int* colI = eidx + NE;   // receivers

  pre_kernel<<<(NE + 255) / 256, 256, 0, stream>>>(rowI, colI, batch, eg_arr, cnt);
  scan_kernel<<<1, 1024, 0, stream>>>(cnt, offs, cur);
  fill_kernel<<<(NE + 255) / 256, 256, 0, stream>>>(colI, cur, eidlist);

  mlp_kernel<0><<<NE / 64, 256, 0, stream>>>(
      eb, xb, ub, nullptr, rowI, colI, batch, nullptr, nullptr, nullptr,
      eW1T, eW2T, eb1, eb2, eg, ebt, outE, nullptr, NE);
  seg_e2g_kernel<<<1000, 256, 0, stream>>>(outE, eg_arr, e2g_part);
  e2g_reduce_kernel<<<32, 256, 0, stream>>>(e2g_part, e2g);
  mlp_kernel<1><<<(NN + 63) / 64, 256, 0, stream>>>(
      nullptr, xb, ub, outE, nullptr, nullptr, batch, offs, cnt, eidlist,
      nW1T, nW2T, nb1, nb2, ng, nbt, outX, n2g, NN);
  glob_kernel<<<NG, 128, 0, stream>>>(u, n2g, e2g, gW1, gb1, gW2, gb2, gg, gbt,
                                      outU);
}

// Round 6
// 1068.132 us; speedup vs baseline: 1.6715x; 1.2691x over previous
//
#include <hip/hip_runtime.h>
#include <hip/hip_bf16.h>

typedef __attribute__((ext_vector_type(8))) short bf16x8;
typedef __attribute__((ext_vector_type(4))) float f32x4;

#define EPSV 1e-5f
#define NN 50000
#define NE 800000
#define NG 64

__device__ __forceinline__ unsigned short f2bf(float f) {
  union { float f; unsigned u; } v; v.f = f;
  unsigned r = v.u + 0x7FFFu + ((v.u >> 16) & 1u);
  return (unsigned short)(r >> 16);
}

// ---------------- conversion kernels ----------------

__global__ __launch_bounds__(256) void cvt_vec_kernel(
    const float* __restrict__ x, const float* __restrict__ e,
    unsigned short* __restrict__ xb, unsigned short* __restrict__ eb) {
  const int NX4 = (NN * 128) / 4;
  const int NE4 = (NE * 32) / 4;
  const int total = NX4 + NE4;
  for (int idx = blockIdx.x * 256 + threadIdx.x; idx < total;
       idx += gridDim.x * 256) {
    float4 v = (idx < NX4) ? ((const float4*)x)[idx]
                           : ((const float4*)e)[idx - NX4];
    ushort4 o;
    o.x = f2bf(v.x); o.y = f2bf(v.y); o.z = f2bf(v.z); o.w = f2bf(v.w);
    if (idx < NX4) ((ushort4*)xb)[idx] = o;
    else           ((ushort4*)eb)[idx - NX4] = o;
  }
}

__global__ __launch_bounds__(256) void cvt_small_kernel(
    const float* __restrict__ u,
    const float* __restrict__ eW1, const float* __restrict__ eW2,
    const float* __restrict__ nW1, const float* __restrict__ nW2,
    unsigned short* __restrict__ ub,
    unsigned short* __restrict__ eW1T, unsigned short* __restrict__ eW2T,
    unsigned short* __restrict__ nW1T, unsigned short* __restrict__ nW2T) {
  int i = blockIdx.x * 256 + threadIdx.x;
  const int R0 = NG * 32;
  const int R1 = R0 + 128 * 320;
  const int R2 = R1 + 128 * 128;
  const int R3 = R2 + 128 * 320;
  const int R4 = R3 + 128 * 128;
  if (i < R0) {
    ub[i] = f2bf(u[i]);
  } else if (i < R1) {
    int j = i - R0; int n = j / 320, k = j % 320;
    eW1T[j] = f2bf(eW1[k * 128 + n]);
  } else if (i < R2) {
    int j = i - R1; int n = j / 128, k = j % 128;
    eW2T[j] = f2bf(eW2[k * 128 + n]);
  } else if (i < R3) {
    int j = i - R2; int n = j / 320, k = j % 320;
    nW1T[j] = (k < 288) ? f2bf(nW1[k * 128 + n]) : (unsigned short)0;
  } else if (i < R4) {
    int j = i - R3; int n = j / 128, k = j % 128;
    nW2T[j] = f2bf(nW2[k * 128 + n]);
  }
}

// ---------------- CSR construction (receiver + sender) ----------------

__global__ __launch_bounds__(256) void pre_kernel(
    const int* __restrict__ rowIdx, const int* __restrict__ colIdx,
    int* __restrict__ cnt_r, int* __restrict__ cnt_s) {
  int i = blockIdx.x * 256 + threadIdx.x;
  if (i < NE) {
    atomicAdd(&cnt_r[colIdx[i]], 1);
    atomicAdd(&cnt_s[rowIdx[i]], 1);
  }
}

__global__ __launch_bounds__(1024) void scan_kernel(
    const int* __restrict__ cnt, int* __restrict__ offs,
    int* __restrict__ cur) {
  __shared__ int sums[1024];
  const int t = threadIdx.x;
  const int base = t * 49;
  int s = 0;
  for (int j = 0; j < 49; ++j) {
    int idx = base + j;
    if (idx < NN) s += cnt[idx];
  }
  sums[t] = s;
  __syncthreads();
  for (int off = 1; off < 1024; off <<= 1) {
    int add = (t >= off) ? sums[t - off] : 0;
    __syncthreads();
    sums[t] += add;
    __syncthreads();
  }
  int run = (t == 0) ? 0 : sums[t - 1];
  for (int j = 0; j < 49; ++j) {
    int idx = base + j;
    if (idx < NN) {
      offs[idx] = run; cur[idx] = run;
      run += cnt[idx];
    }
  }
}

__global__ __launch_bounds__(256) void fill_kernel(
    const int* __restrict__ colIdx, int* __restrict__ cur,
    int* __restrict__ eidlist) {
  int i = blockIdx.x * 256 + threadIdx.x;
  if (i < NE) {
    int p = atomicAdd(&cur[colIdx[i]], 1);
    eidlist[p] = i;
  }
}

// sender-sorted list + per-position graph id (non-decreasing since batch sorted)
__global__ __launch_bounds__(256) void fill2_kernel(
    const int* __restrict__ rowIdx, const int* __restrict__ batch,
    int* __restrict__ cur_s, int* __restrict__ eidlist_s,
    int* __restrict__ gs) {
  int i = blockIdx.x * 256 + threadIdx.x;
  if (i < NE) {
    const int r = rowIdx[i];
    const int p = atomicAdd(&cur_s[r], 1);
    eidlist_s[p] = i;
    gs[p] = batch[r];
  }
}

// ---------------- fused MLP kernel (edge MODE=0 / node MODE=1) ----------------
// 64 rows per block, 256 threads = 4 waves; wave w owns rows w*16..w*16+15.
template <int MODE>
__global__ __launch_bounds__(256, 2) void mlp_kernel(
    const unsigned short* __restrict__ ebuf,
    const unsigned short* __restrict__ xb,
    const unsigned short* __restrict__ ub,
    const float* __restrict__ aggsrc,
    const int* __restrict__ rowIdx, const int* __restrict__ colIdx,
    const int* __restrict__ batch,
    const int* __restrict__ offs, const int* __restrict__ cnt,
    const int* __restrict__ eidlist,
    const unsigned short* __restrict__ W1T,
    const unsigned short* __restrict__ W2T,
    const float* __restrict__ b1, const float* __restrict__ b2,
    const float* __restrict__ gam, const float* __restrict__ bet,
    float* __restrict__ out, float* __restrict__ aggout, int nRows) {
  constexpr int USZ = (MODE == 1) ? 50176 : 41984;
  __shared__ __align__(16) char U[USZ];
  __shared__ __align__(16) unsigned short Bsm[128][72];
  __shared__ float cb1[128], cb2[128], cg[128], cbt[128];
  unsigned short (*Asm)[328] = (unsigned short(*)[328])U;
  unsigned short (*Hsm)[136] = (unsigned short(*)[136])U;
  float* bins = (float*)(U + 17408);

  const int tid = threadIdx.x;
  if (tid < 128) {
    cb1[tid] = b1[tid]; cb2[tid] = b2[tid];
    cg[tid] = gam[tid]; cbt[tid] = bet[tid];
  }

  // ---- stage A tile: 4 threads per row ----
  {
    const int r = tid >> 2, q = tid & 3;
    const int grow = blockIdx.x * 64 + r;
    if (MODE == 0) {
      const int rcv = colIdx[grow];
      const int snd = rowIdx[grow];
      const int g = batch[snd];
      const uint4* esrc = (const uint4*)(ebuf + (size_t)grow * 32);
      const uint4* xr = (const uint4*)(xb + (size_t)rcv * 128);
      const uint4* xs = (const uint4*)(xb + (size_t)snd * 128);
      const uint4* us = (const uint4*)(ub + g * 32);
#pragma unroll
      for (int c = 0; c < 10; ++c) {
        const int cc = q * 10 + c;
        uint4 v;
        if (cc < 4)       v = esrc[cc];
        else if (cc < 20) v = xr[cc - 4];
        else if (cc < 36) v = xs[cc - 20];
        else              v = us[cc - 36];
        *(uint4*)&Asm[r][cc * 8] = v;
      }
    } else {
      const bool valid = grow < nRows;
      const uint4 zero = {0u, 0u, 0u, 0u};
      if (valid) {
        const uint4* xs = (const uint4*)(xb + (size_t)grow * 128 + q * 32);
#pragma unroll
        for (int k = 0; k < 4; ++k) *(uint4*)&Asm[r][q * 32 + k * 8] = xs[k];
      } else {
#pragma unroll
        for (int k = 0; k < 4; ++k) *(uint4*)&Asm[r][q * 32 + k * 8] = zero;
      }
      float4 a[8];
#pragma unroll
      for (int k = 0; k < 8; ++k) a[k] = float4{0.f, 0.f, 0.f, 0.f};
      if (valid) {
        const int start = offs[grow];
        const int deg = cnt[grow];
        int j = 0;
        for (; j + 2 <= deg; j += 2) {
          const int e0 = eidlist[start + j], e1 = eidlist[start + j + 1];
          const float4* s0 = (const float4*)(aggsrc + (size_t)e0 * 128 + q * 32);
          const float4* s1 = (const float4*)(aggsrc + (size_t)e1 * 128 + q * 32);
#pragma unroll
          for (int k = 0; k < 8; ++k) {
            float4 v0 = s0[k], v1 = s1[k];
            a[k].x += v0.x + v1.x; a[k].y += v0.y + v1.y;
            a[k].z += v0.z + v1.z; a[k].w += v0.w + v1.w;
          }
        }
        if (j < deg) {
          const int e0 = eidlist[start + j];
          const float4* s0 = (const float4*)(aggsrc + (size_t)e0 * 128 + q * 32);
#pragma unroll
          for (int k = 0; k < 8; ++k) {
            float4 v0 = s0[k];
            a[k].x += v0.x; a[k].y += v0.y; a[k].z += v0.z; a[k].w += v0.w;
          }
        }
      }
#pragma unroll
      for (int k = 0; k < 8; ++k) {
        ushort4 o;
        o.x = f2bf(a[k].x); o.y = f2bf(a[k].y);
        o.z = f2bf(a[k].z); o.w = f2bf(a[k].w);
        *(ushort4*)&Asm[r][128 + q * 32 + k * 4] = o;
      }
      const int g = valid ? batch[grow] : 0;
      uint4 uv = valid ? *(const uint4*)(ub + g * 32 + q * 8) : zero;
      *(uint4*)&Asm[r][256 + q * 8] = uv;
      *(uint4*)&Asm[r][288 + q * 8] = zero;
    }
  }

  const int w = tid >> 6;
  const int lane = tid & 63;
  const int l15 = lane & 15, lg = lane >> 4;

  f32x4 acc[8];
#pragma unroll
  for (int ni = 0; ni < 8; ++ni) acc[ni] = f32x4{0.f, 0.f, 0.f, 0.f};

  // ---- GEMM1: C1[64x128] = A[64x320] @ W1 ----
  for (int kc = 0; kc < 5; ++kc) {
    {
      const int n = tid >> 1, half = tid & 1;
      const uint4* src = (const uint4*)(W1T + (size_t)n * 320 + kc * 64 + half * 32);
#pragma unroll
      for (int k = 0; k < 4; ++k)
        *(uint4*)&Bsm[n][half * 32 + k * 8] = src[k];
    }
    __syncthreads();
    bf16x8 a0 = *(bf16x8*)&Asm[w * 16 + l15][kc * 64 + lg * 8];
    bf16x8 a1 = *(bf16x8*)&Asm[w * 16 + l15][kc * 64 + 32 + lg * 8];
#pragma unroll
    for (int ni = 0; ni < 8; ++ni) {
      bf16x8 bb0 = *(bf16x8*)&Bsm[ni * 16 + l15][lg * 8];
      bf16x8 bb1 = *(bf16x8*)&Bsm[ni * 16 + l15][32 + lg * 8];
      acc[ni] = __builtin_amdgcn_mfma_f32_16x16x32_bf16(a0, bb0, acc[ni], 0, 0, 0);
      acc[ni] = __builtin_amdgcn_mfma_f32_16x16x32_bf16(a1, bb1, acc[ni], 0, 0, 0);
    }
    __syncthreads();
  }

  // ---- h1 = relu(C1 + b1) -> Hsm (aliases dead Asm); MODE1: zero bins ----
#pragma unroll
  for (int ni = 0; ni < 8; ++ni) {
    const int ncol = l15 + ni * 16;
    const float bias = cb1[ncol];
#pragma unroll
    for (int reg = 0; reg < 4; ++reg) {
      const int mrow = w * 16 + lg * 4 + reg;
      Hsm[mrow][ncol] = f2bf(fmaxf(acc[ni][reg] + bias, 0.f));
    }
  }
  if (MODE == 1) {
    for (int i = tid; i < NG * 128; i += 256) bins[i] = 0.f;
  }

  // ---- GEMM2: C2 = H1[64x128] @ W2 ----
  f32x4 acc2[8];
#pragma unroll
  for (int ni = 0; ni < 8; ++ni) acc2[ni] = f32x4{0.f, 0.f, 0.f, 0.f};
  for (int kc = 0; kc < 2; ++kc) {
    {
      const int n = tid >> 1, half = tid & 1;
      const uint4* src = (const uint4*)(W2T + (size_t)n * 128 + kc * 64 + half * 32);
#pragma unroll
      for (int k = 0; k < 4; ++k)
        *(uint4*)&Bsm[n][half * 32 + k * 8] = src[k];
    }
    __syncthreads();
    bf16x8 a0 = *(bf16x8*)&Hsm[w * 16 + l15][kc * 64 + lg * 8];
    bf16x8 a1 = *(bf16x8*)&Hsm[w * 16 + l15][kc * 64 + 32 + lg * 8];
#pragma unroll
    for (int ni = 0; ni < 8; ++ni) {
      bf16x8 bb0 = *(bf16x8*)&Bsm[ni * 16 + l15][lg * 8];
      bf16x8 bb1 = *(bf16x8*)&Bsm[ni * 16 + l15][32 + lg * 8];
      acc2[ni] = __builtin_amdgcn_mfma_f32_16x16x32_bf16(a0, bb0, acc2[ni], 0, 0, 0);
      acc2[ni] = __builtin_amdgcn_mfma_f32_16x16x32_bf16(a1, bb1, acc2[ni], 0, 0, 0);
    }
    __syncthreads();
  }

  // ---- epilogue ----
  float hv[8][4];
  float sreg[4] = {0.f, 0.f, 0.f, 0.f}, ssreg[4] = {0.f, 0.f, 0.f, 0.f};
#pragma unroll
  for (int ni = 0; ni < 8; ++ni) {
    const int ncol = l15 + ni * 16;
    const float bias = cb2[ncol];
#pragma unroll
    for (int reg = 0; reg < 4; ++reg) {
      const float h = fmaxf(acc2[ni][reg] + bias, 0.f);
      hv[ni][reg] = h;
      sreg[reg] += h; ssreg[reg] += h * h;
    }
  }
#pragma unroll
  for (int reg = 0; reg < 4; ++reg) {
    float s = sreg[reg], ss = ssreg[reg];
#pragma unroll
    for (int off = 1; off < 16; off <<= 1) {
      s += __shfl_xor(s, off, 64);
      ss += __shfl_xor(ss, off, 64);
    }
    sreg[reg] = s; ssreg[reg] = ss;
  }
#pragma unroll
  for (int reg = 0; reg < 4; ++reg) {
    const int mrow = w * 16 + lg * 4 + reg;
    const int grow = blockIdx.x * 64 + mrow;
    if (MODE == 1 && grow >= nRows) continue;
    const float mu = sreg[reg] * (1.f / 128.f);
    const float var = ssreg[reg] * (1.f / 128.f) - mu * mu;
    const float rstd = rsqrtf(var + EPSV);
    int g = 0;
    if (MODE == 1) g = batch[grow];
#pragma unroll
    for (int ni = 0; ni < 8; ++ni) {
      const int ncol = l15 + ni * 16;
      const float y = cg[ncol] * (hv[ni][reg] - mu) * rstd + cbt[ncol];
      out[(size_t)grow * 128 + ncol] = y;
      if (MODE == 1) atomicAdd(&bins[g * 128 + ncol], y);
    }
  }
  if (MODE == 1) {
    __syncthreads();
    const int first = blockIdx.x * 64;
    const int last = min(first + 63, nRows - 1);
    const int gmin = batch[first], gmax = batch[last];
    const int cntf = (gmax - gmin + 1) * 128;
    for (int i = tid; i < cntf; i += 256)
      atomicAdd(&aggout[gmin * 128 + i], bins[gmin * 128 + i]);
  }
}

// ---- edge->global: sender-sorted streaming reduce, register accumulation ----
// g = gs[pos] is non-decreasing; all 64 lanes of a wave share pos -> uniform
// branch; flush to global e2g only on g-change (~410K atomics total).
__global__ __launch_bounds__(256) void seg_sorted_kernel(
    const float* __restrict__ data, const int* __restrict__ eidl,
    const int* __restrict__ gs, float* __restrict__ e2g) {
  const int t = threadIdx.x;
  const int col = t & 127, sub = t >> 7;
  const int start = blockIdx.x * 800;   // 1000 blocks x 800 positions
  int gcur = gs[start + sub];
  float acc = 0.f;
  for (int it = 0; it < 50; ++it) {
    const int base = start + sub + it * 16;
    int eid[8], g[8];
#pragma unroll
    for (int j = 0; j < 8; ++j) {
      eid[j] = eidl[base + j * 2];
      g[j]   = gs[base + j * 2];
    }
    float v[8];
#pragma unroll
    for (int j = 0; j < 8; ++j)
      v[j] = data[(size_t)eid[j] * 128 + col];
#pragma unroll
    for (int j = 0; j < 8; ++j) {
      if (g[j] != gcur) {
        atomicAdd(&e2g[gcur * 128 + col], acc);
        gcur = g[j]; acc = 0.f;
      }
      acc += v[j];
    }
  }
  atomicAdd(&e2g[gcur * 128 + col], acc);
}

// ---------------- global MLP (tiny) ----------------
__global__ __launch_bounds__(128) void glob_kernel(
    const float* __restrict__ u, const float* __restrict__ n2g,
    const float* __restrict__ e2g,
    const float* __restrict__ gW1, const float* __restrict__ gb1,
    const float* __restrict__ gW2, const float* __restrict__ gb2,
    const float* __restrict__ gg, const float* __restrict__ gbt,
    float* __restrict__ outU) {
  __shared__ float in[288];
  __shared__ float h1[128];
  __shared__ float red[4];
  const int g = blockIdx.x, t = threadIdx.x;
  if (t < 32) in[t] = u[g * 32 + t];
  in[32 + t] = n2g[g * 128 + t];
  in[160 + t] = e2g[g * 128 + t];
  __syncthreads();
  float a = gb1[t];
  for (int k = 0; k < 288; ++k) a += in[k] * gW1[k * 128 + t];
  h1[t] = fmaxf(a, 0.f);
  __syncthreads();
  float h = gb2[t];
  for (int k = 0; k < 128; ++k) h += h1[k] * gW2[k * 128 + t];
  h = fmaxf(h, 0.f);
  float s = h, ss = h * h;
  for (int off = 1; off < 64; off <<= 1) {
    s += __shfl_xor(s, off, 64);
    ss += __shfl_xor(ss, off, 64);
  }
  if ((t & 63) == 0) { red[(t >> 6) * 2] = s; red[(t >> 6) * 2 + 1] = ss; }
  __syncthreads();
  const float S = red[0] + red[2], SS = red[1] + red[3];
  const float mu = S * (1.f / 128.f);
  const float var = SS * (1.f / 128.f) - mu * mu;
  const float rstd = rsqrtf(var + EPSV);
  outU[g * 128 + t] = gg[t] * (h - mu) * rstd + gbt[t];
}

// ---------------- launch ----------------
extern "C" void kernel_launch(void* const* d_in, const int* in_sizes, int n_in,
                              void* d_out, int out_size, void* d_ws,
                              size_t ws_size, hipStream_t stream) {
  const float* x   = (const float*)d_in[0];
  const float* e   = (const float*)d_in[1];
  const float* u   = (const float*)d_in[2];
  const int* eidx  = (const int*)d_in[3];
  const int* batch = (const int*)d_in[4];
  const float* eW1 = (const float*)d_in[5];
  const float* eb1 = (const float*)d_in[6];
  const float* eW2 = (const float*)d_in[7];
  const float* eb2 = (const float*)d_in[8];
  const float* eg  = (const float*)d_in[9];
  const float* ebt = (const float*)d_in[10];
  const float* nW1 = (const float*)d_in[11];
  const float* nb1 = (const float*)d_in[12];
  const float* nW2 = (const float*)d_in[13];
  const float* nb2 = (const float*)d_in[14];
  const float* ng  = (const float*)d_in[15];
  const float* nbt = (const float*)d_in[16];
  const float* gW1 = (const float*)d_in[17];
  const float* gb1 = (const float*)d_in[18];
  const float* gW2 = (const float*)d_in[19];
  const float* gb2 = (const float*)d_in[20];
  const float* gg  = (const float*)d_in[21];
  const float* gbt = (const float*)d_in[22];

  char* ws = (char*)d_ws;
  float* e2g           = (float*)(ws + 0);          //    32,768
  float* n2g           = (float*)(ws + 32768);      //    32,768
  int*   cnt_r         = (int*)  (ws + 65536);      //   200,000
  int*   cnt_s         = (int*)  (ws + 265536);     //   200,000
  int*   offs_r        = (int*)  (ws + 465536);     //   200,000
  int*   cur_r         = (int*)  (ws + 665536);     //   200,000
  int*   offs_s        = (int*)  (ws + 865536);     //   200,000
  int*   cur_s         = (int*)  (ws + 1065536);    //   200,000
  int*   eidlist_r     = (int*)  (ws + 1265536);    // 3,200,000
  int*   eidlist_s     = (int*)  (ws + 4465536);    // 3,200,000
  int*   gs            = (int*)  (ws + 7665536);    // 3,200,000
  unsigned short* xb   = (unsigned short*)(ws + 10865536);  // 12,800,000
  unsigned short* eb   = (unsigned short*)(ws + 23665536);  // 51,200,000
  unsigned short* ub   = (unsigned short*)(ws + 74865536);  //     4,096
  unsigned short* eW1T = (unsigned short*)(ws + 74869632);  //    81,920
  unsigned short* eW2T = (unsigned short*)(ws + 74951552);  //    32,768
  unsigned short* nW1T = (unsigned short*)(ws + 74984320);  //    81,920
  unsigned short* nW2T = (unsigned short*)(ws + 75066240);  //    32,768
  // total ws use: ~75.1 MB

  // zero e2g + n2g + cnt_r + cnt_s (contiguous)
  hipMemsetAsync(ws, 0, 465536, stream);

  cvt_vec_kernel<<<2048, 256, 0, stream>>>(x, e, xb, eb);
  cvt_small_kernel<<<456, 256, 0, stream>>>(u, eW1, eW2, nW1, nW2, ub, eW1T,
                                            eW2T, nW1T, nW2T);

  float* outX = (float*)d_out;                 // [50000][128]
  float* outE = outX + (size_t)NN * 128;       // [800000][128]
  float* outU = outE + (size_t)NE * 128;       // [64][128]

  const int* rowI = eidx;        // senders
  const int* colI = eidx + NE;   // receivers

  pre_kernel<<<(NE + 255) / 256, 256, 0, stream>>>(rowI, colI, cnt_r, cnt_s);
  scan_kernel<<<1, 1024, 0, stream>>>(cnt_r, offs_r, cur_r);
  scan_kernel<<<1, 1024, 0, stream>>>(cnt_s, offs_s, cur_s);
  fill_kernel<<<(NE + 255) / 256, 256, 0, stream>>>(colI, cur_r, eidlist_r);
  fill2_kernel<<<(NE + 255) / 256, 256, 0, stream>>>(rowI, batch, cur_s,
                                                     eidlist_s, gs);

  mlp_kernel<0><<<NE / 64, 256, 0, stream>>>(
      eb, xb, ub, nullptr, rowI, colI, batch, nullptr, nullptr, nullptr,
      eW1T, eW2T, eb1, eb2, eg, ebt, outE, nullptr, NE);
  seg_sorted_kernel<<<1000, 256, 0, stream>>>(outE, eidlist_s, gs, e2g);
  mlp_kernel<1><<<(NN + 63) / 64, 256, 0, stream>>>(
      nullptr, xb, ub, outE, nullptr, nullptr, batch, offs_r, cnt_r, eidlist_r,
      nW1T, nW2T, nb1, nb2, ng, nbt, outX, n2g, NN);
  glob_kernel<<<NG, 128, 0, stream>>>(u, n2g, e2g, gW1, gb1, gW2, gb2, gg, gbt,
                                      outU);
}